// Round 1
// baseline (500.260 us; speedup 1.0000x reference)
//
#include <hip/hip_runtime.h>

#define D 32

__global__ void count_kernel(const int* __restrict__ src, const int* __restrict__ dst,
                             int* __restrict__ degI, int* __restrict__ cntI, int E) {
    int j = blockIdx.x * blockDim.x + threadIdx.x;
    if (j < E) {
        atomicAdd(&degI[dst[j]], 1);
        atomicAdd(&cntI[src[j]], 1);
    }
}

__global__ void dinv_kernel(const int* __restrict__ degI, float* __restrict__ dinv, int N) {
    int i = blockIdx.x * blockDim.x + threadIdx.x;
    if (i < N) dinv[i] = rsqrtf((float)(degI[i] + 1));  // +1 self-loop; deg>=1 always
}

// hs[i][d] = (X[i] @ W)[d] * dinv[i]; 8 rows per 256-thread block
__global__ void matmul_scale_kernel(const float* __restrict__ X, const float* __restrict__ W,
                                    const float* __restrict__ dinv, float* __restrict__ hs,
                                    int N) {
    __shared__ float Wl[D * D];   // 4 KB
    __shared__ float Xl[8 * D];   // 1 KB
    int tid = threadIdx.x;
    for (int k = tid; k < D * D; k += 256) Wl[k] = W[k];
    int row0 = blockIdx.x * 8;
    int g = row0 * D + tid;
    Xl[tid] = (g < N * D) ? X[g] : 0.f;
    __syncthreads();
    int r = tid >> 5;   // local row 0..7
    int d = tid & 31;
    int row = row0 + r;
    if (row < N) {
        float acc = 0.f;
        #pragma unroll
        for (int k = 0; k < D; ++k) acc += Xl[r * D + k] * Wl[k * D + d];
        hs[row * D + d] = acc * dinv[row];
    }
}

// S[dst] += hs[src], one thread per (edge, feature)
__global__ void scatter_conv_kernel(const int* __restrict__ src, const int* __restrict__ dst,
                                    const float* __restrict__ hs, float* __restrict__ S, int ED) {
    int idx = blockIdx.x * blockDim.x + threadIdx.x;
    if (idx < ED) {
        int j = idx >> 5, d = idx & 31;
        atomicAdd(&S[dst[j] * D + d], hs[src[j] * D + d]);
    }
}

// h2 = relu(dinv[i]*(S+hs) + b), in-place into S
__global__ void h2_kernel(float* __restrict__ S, const float* __restrict__ hs,
                          const float* __restrict__ dinv, const float* __restrict__ b, int ND) {
    int idx = blockIdx.x * blockDim.x + threadIdx.x;
    if (idx < ND) {
        int i = idx >> 5, d = idx & 31;
        float v = dinv[i] * (S[idx] + hs[idx]) + b[d];
        S[idx] = fmaxf(v, 0.f);
    }
}

// out[src] += (h2[src]-h2[dst])^2   (P=2)
__global__ void edge_pow_kernel(const int* __restrict__ src, const int* __restrict__ dst,
                                const float* __restrict__ h2, float* __restrict__ out, int ED) {
    int idx = blockIdx.x * blockDim.x + threadIdx.x;
    if (idx < ED) {
        int j = idx >> 5, d = idx & 31;
        float v = h2[src[j] * D + d] - h2[dst[j] * D + d];
        atomicAdd(&out[src[j] * D + d], v * v);
    }
}

__global__ void finalize_kernel(float* __restrict__ out, const int* __restrict__ cntI, int ND) {
    int idx = blockIdx.x * blockDim.x + threadIdx.x;
    if (idx < ND) {
        int i = idx >> 5;
        float c = fmaxf((float)cntI[i], 1.f);
        out[idx] = tanhf(out[idx] / c);
    }
}

extern "C" void kernel_launch(void* const* d_in, const int* in_sizes, int n_in,
                              void* d_out, int out_size, void* d_ws, size_t ws_size,
                              hipStream_t stream) {
    const float* X  = (const float*)d_in[0];
    const int*   ei = (const int*)d_in[1];
    const float* W  = (const float*)d_in[2];
    const float* b  = (const float*)d_in[3];
    int N = in_sizes[0] / D;
    int E = in_sizes[1] / 2;
    const int* src = ei;
    const int* dst = ei + E;
    float* out = (float*)d_out;

    float* hs   = (float*)d_ws;              // N*D
    float* S    = hs + (size_t)N * D;        // N*D (reused as h2)
    float* dinv = S + (size_t)N * D;         // N
    int*   degI = (int*)(dinv + N);          // N
    int*   cntI = degI + N;                  // N

    hipMemsetAsync(S, 0, (size_t)N * D * sizeof(float), stream);
    hipMemsetAsync(degI, 0, (size_t)2 * N * sizeof(int), stream);  // degI+cntI contiguous
    hipMemsetAsync(d_out, 0, (size_t)N * D * sizeof(float), stream);

    int ND = N * D;
    int ED = E * D;
    count_kernel<<<(E + 255) / 256, 256, 0, stream>>>(src, dst, degI, cntI, E);
    dinv_kernel<<<(N + 255) / 256, 256, 0, stream>>>(degI, dinv, N);
    matmul_scale_kernel<<<(N + 7) / 8, 256, 0, stream>>>(X, W, dinv, hs, N);
    scatter_conv_kernel<<<(ED + 255) / 256, 256, 0, stream>>>(src, dst, hs, S, ED);
    h2_kernel<<<(ND + 255) / 256, 256, 0, stream>>>(S, hs, dinv, b, ND);
    edge_pow_kernel<<<(ED + 255) / 256, 256, 0, stream>>>(src, dst, S, out, ED);
    finalize_kernel<<<(ND + 255) / 256, 256, 0, stream>>>(out, cntI, ND);
}